// Round 1
// 670.540 us; speedup vs baseline: 1.3665x; 1.3665x over previous
//
#include <hip/hip_runtime.h>
#include <hip/hip_bf16.h>
#include <cstdint>

#define M_DIM 4096
#define K_DIM 4096
#define N_DIM 11008
#define NT_K  (K_DIM / 64)          // 64 K-tiles of BK=64

typedef __attribute__((ext_vector_type(8))) short short8;
typedef __attribute__((ext_vector_type(4))) float floatx4;

__device__ __forceinline__ unsigned short f2bf(float f) {
    union { float f; unsigned u; } v; v.f = f;
    unsigned r = v.u + 0x7FFFu + ((v.u >> 16) & 1u);   // round-to-nearest-even
    return (unsigned short)(r >> 16);
}

__device__ __forceinline__ void async_copy16(const ushort* g, const ushort* l) {
    __builtin_amdgcn_global_load_lds(
        (const __attribute__((address_space(1))) void*)(uintptr_t)(const void*)g,
        (__attribute__((address_space(3))) void*)(uintptr_t)(const void*)l,
        16, 0, 0);
}

// Convert one row of x (fp32 -> bf16) and compute its row sum in fp32.
__global__ void prep_x_kernel(const float* __restrict__ x, ushort* __restrict__ xb,
                              float* __restrict__ s) {
    const int row = blockIdx.x;
    const int tid = threadIdx.x;                 // 256 threads
    const float*  xr = x  + (size_t)row * K_DIM;
    ushort*       xo = xb + (size_t)row * K_DIM;
    float sum = 0.f;
#pragma unroll
    for (int i = 0; i < 2; ++i) {
        int e = (tid + i * 256) * 8;             // 8 floats per unit
        float4 v0 = *(const float4*)(xr + e);
        float4 v1 = *(const float4*)(xr + e + 4);
        sum += v0.x + v0.y + v0.z + v0.w + v1.x + v1.y + v1.z + v1.w;
        short8 o;
        o[0] = f2bf(v0.x); o[1] = f2bf(v0.y); o[2] = f2bf(v0.z); o[3] = f2bf(v0.w);
        o[4] = f2bf(v1.x); o[5] = f2bf(v1.y); o[6] = f2bf(v1.z); o[7] = f2bf(v1.w);
        *(short8*)(xo + e) = o;
    }
#pragma unroll
    for (int off = 32; off > 0; off >>= 1) sum += __shfl_down(sum, off, 64);
    __shared__ float red[4];
    if ((tid & 63) == 0) red[tid >> 6] = sum;
    __syncthreads();
    if (tid == 0) s[row] = red[0] + red[1] + red[2] + red[3];
}

// Convert int8-valued int32 weights -> bf16 (exact). One ushort8 (16B) per thread.
__global__ void prep_w_kernel(const int* __restrict__ w, ushort* __restrict__ wb) {
    size_t i = (size_t)blockIdx.x * blockDim.x + threadIdx.x;
    const int4* wi = (const int4*)w;
    int4 v0 = wi[2 * i];
    int4 v1 = wi[2 * i + 1];
    short8 o;
    o[0] = f2bf((float)v0.x); o[1] = f2bf((float)v0.y);
    o[2] = f2bf((float)v0.z); o[3] = f2bf((float)v0.w);
    o[4] = f2bf((float)v1.x); o[5] = f2bf((float)v1.y);
    o[6] = f2bf((float)v1.z); o[7] = f2bf((float)v1.w);
    ((short8*)wb)[i] = o;
}

// ---------------------------------------------------------------------------
// 256x256 tile, BK=64, 8 waves (2M x 4N), 4 phases per K-tile, counted vmcnt.
// LDS: [slot][A|B][256 rows][64 k] bf16, double buffered = 128 KiB.
// T2 swizzle: 16B chunk index XORed with (row&7) on both write-source and read.
// ---------------------------------------------------------------------------

#define BAR_MID()                               \
    __builtin_amdgcn_sched_barrier(0);          \
    __builtin_amdgcn_s_barrier();               \
    asm volatile("s_waitcnt lgkmcnt(0)");       \
    __builtin_amdgcn_sched_barrier(0)

#define BAR_END()                               \
    __builtin_amdgcn_sched_barrier(0);          \
    __builtin_amdgcn_s_barrier()

#define LOAD_A(q)                                                             \
    _Pragma("unroll")                                                         \
    for (int fl = 0; fl < 2; ++fl)                                            \
        _Pragma("unroll")                                                     \
        for (int ks = 0; ks < 2; ++ks)                                        \
            a[fl][ks] = *(const short8*)(Ar + aoff[ks] + (q) * 2048 + fl * 1024)

#define MFMA_Q(q)                                                             \
    __builtin_amdgcn_s_setprio(1);                                            \
    _Pragma("unroll")                                                         \
    for (int fl = 0; fl < 2; ++fl)                                            \
        _Pragma("unroll")                                                     \
        for (int fn = 0; fn < 4; ++fn)                                        \
            _Pragma("unroll")                                                 \
            for (int ks = 0; ks < 2; ++ks)                                    \
                acc[(q) * 2 + fl][fn] = __builtin_amdgcn_mfma_f32_16x16x32_bf16( \
                    a[fl][ks], b[fn][ks], acc[(q) * 2 + fl][fn], 0, 0, 0);    \
    __builtin_amdgcn_s_setprio(0)

__global__ __launch_bounds__(512) void gemm_kernel(
        const ushort* __restrict__ xb, const ushort* __restrict__ wb,
        const float* __restrict__ s, const float* __restrict__ scale,
        const float* __restrict__ offset, const float* __restrict__ bias,
        float* __restrict__ y) {
    __shared__ ushort lds[2][2][256 * 64];     // 128 KiB

    const int tid  = threadIdx.x;
    const int lane = tid & 63;
    const int wave = tid >> 6;          // 0..7
    const int wm   = wave >> 2;         // 0..1  (M half)
    const int wn   = wave & 3;          // 0..3  (N quarter)
    const int r15  = lane & 15;
    const int quad = lane >> 4;

    // XCD-aware bijective swizzle: 688 blocks = 8 XCDs x 86 contiguous work-ids.
    // Within an XCD, m_tile is the fast axis -> one 2 MiB B-panel stays L2-hot.
    const int wg  = blockIdx.x;
    const int swz = (wg & 7) * 86 + (wg >> 3);
    const int m0  = (swz & 15) * 256;
    const int n0  = (swz >> 4) * 256;

    // --- staging addressing (linear LDS dest, pre-swizzled global source) ---
    // lane's linear dest byte off = l*8192 + wave*1024 + lane*16
    //   -> row = l*64 + wave*8 + (lane>>3), phys 16B-chunk = lane&7
    //   source chunk = phys ^ (row&7) = (lane&7) ^ (lane>>3)
    const int    srow = wave * 8 + (lane >> 3);
    const int    scol = ((lane & 7) ^ (lane >> 3)) * 8;
    const ushort* aSrc = xb + (size_t)(m0 + srow) * K_DIM + scol;
    const ushort* bSrc = wb + (size_t)(n0 + srow) * K_DIM + scol;
    const int    sdst = wave * 512;            // element offset (+ l*4096)

    // --- swizzled read offsets: chunk (ks*4+quad) ^ (row&7), row&7 == r15&7 ---
    const int x7 = r15 & 7;
    int aoff[2], boff[2];
#pragma unroll
    for (int ks = 0; ks < 2; ++ks) {
        aoff[ks] = (wm * 128 + r15) * 64 + ((ks * 4 + quad) ^ x7) * 8;
        boff[ks] = (wn *  64 + r15) * 64 + ((ks * 4 + quad) ^ x7) * 8;
    }

    floatx4 acc[8][4] = {};

    // --- prologue: stage A(0), B(0) -> slot0; B(1) -> slot1.  vmcnt(4) keeps
    //     the 4 B(1) loads in flight. ---
#pragma unroll
    for (int l = 0; l < 4; ++l)
        async_copy16(aSrc + (size_t)l * 64 * K_DIM, &lds[0][0][sdst + l * 4096]);
#pragma unroll
    for (int l = 0; l < 4; ++l)
        async_copy16(bSrc + (size_t)l * 64 * K_DIM, &lds[0][1][sdst + l * 4096]);
#pragma unroll
    for (int l = 0; l < 4; ++l)
        async_copy16(bSrc + (size_t)l * 64 * K_DIM + 64, &lds[1][1][sdst + l * 4096]);
    asm volatile("s_waitcnt vmcnt(4)" ::: "memory");
    __builtin_amdgcn_s_barrier();

    for (int t = 0; t < NT_K; ++t) {
        const int c = t & 1;
        const ushort* Ar = &lds[c][0][0];
        ushort*       Aw = &lds[c ^ 1][0][0];   // A(t+1): opposite slot, idle
        ushort*       Bp = &lds[c][1][0];       // B(t): read ph0; B(t+2) staged ph2/3
        const size_t ka = (t + 1 < NT_K) ? (size_t)(t + 1) * 64 : 0;  // clamped
        const size_t kb = (t + 2 < NT_K) ? (size_t)(t + 2) * 64 : 0;  // (garbage
                                                                      //  never read)
        short8 a[2][2], b[4][2];

        // ---- phase 0: all B + A-quad0 ; stage A(t+1) halves 0,1 ----
#pragma unroll
        for (int fn = 0; fn < 4; ++fn)
#pragma unroll
            for (int ks = 0; ks < 2; ++ks)
                b[fn][ks] = *(const short8*)(Bp + boff[ks] + fn * 1024);
        LOAD_A(0);
        async_copy16(aSrc + ka,                        Aw + sdst);
        async_copy16(aSrc + (size_t) 64 * K_DIM + ka,  Aw + sdst + 4096);
        BAR_MID();
        MFMA_Q(0);
        BAR_END();

        // ---- phase 1: A-quad1 ; stage A(t+1) halves 2,3 ----
        LOAD_A(1);
        async_copy16(aSrc + (size_t)128 * K_DIM + ka,  Aw + sdst + 8192);
        async_copy16(aSrc + (size_t)192 * K_DIM + ka,  Aw + sdst + 12288);
        BAR_MID();
        MFMA_Q(1);
        BAR_END();

        // ---- phase 2: A-quad2 ; stage B(t+2) halves 0,1 (B(t) consumed ph0) ----
        LOAD_A(2);
        async_copy16(bSrc + kb,                        Bp + sdst);
        async_copy16(bSrc + (size_t) 64 * K_DIM + kb,  Bp + sdst + 4096);
        BAR_MID();
        MFMA_Q(2);
        BAR_END();

        // ---- phase 3: A-quad3 ; stage B(t+2) halves 2,3 ; counted wait ----
        LOAD_A(3);
        async_copy16(bSrc + (size_t)128 * K_DIM + kb,  Bp + sdst + 8192);
        async_copy16(bSrc + (size_t)192 * K_DIM + kb,  Bp + sdst + 12288);
        BAR_MID();
        MFMA_Q(3);
        // A(t+1)+B(t+1) landed; only the 4 B(t+2) loads may stay in flight.
        asm volatile("s_waitcnt vmcnt(4)" ::: "memory");
        BAR_END();
    }

    // ---- epilogue: y = scale*(acc + off*rowsum) + bias ----
    float sm[8][4];
#pragma unroll
    for (int fm = 0; fm < 8; ++fm)
#pragma unroll
        for (int r = 0; r < 4; ++r)
            sm[fm][r] = s[m0 + wm * 128 + fm * 16 + quad * 4 + r];

#pragma unroll
    for (int fn = 0; fn < 4; ++fn) {
        const int n = n0 + wn * 64 + fn * 16 + r15;
        const float sc = scale[n], of = offset[n], bi = bias[n];
#pragma unroll
        for (int fm = 0; fm < 8; ++fm) {
            const int mb = m0 + wm * 128 + fm * 16 + quad * 4;
#pragma unroll
            for (int r = 0; r < 4; ++r) {
                y[(size_t)(mb + r) * N_DIM + n] =
                    sc * (acc[fm][fn][r] + of * sm[fm][r]) + bi;
            }
        }
    }
}

extern "C" void kernel_launch(void* const* d_in, const int* in_sizes, int n_in,
                              void* d_out, int out_size, void* d_ws, size_t ws_size,
                              hipStream_t stream) {
    const float* x      = (const float*)d_in[0];
    const int*   weight = (const int*)d_in[1];
    const float* scale  = (const float*)d_in[2];
    const float* offset = (const float*)d_in[3];
    const float* bias   = (const float*)d_in[4];
    float*       y      = (float*)d_out;

    // Workspace layout (bytes): xb bf16 M*K | wb bf16 N*K | s fp32 M
    ushort* xb = (ushort*)d_ws;
    ushort* wb = (ushort*)((char*)d_ws + (size_t)M_DIM * K_DIM * 2);
    float*  s  = (float*)((char*)d_ws + (size_t)M_DIM * K_DIM * 2 + (size_t)N_DIM * K_DIM * 2);

    prep_x_kernel<<<M_DIM, 256, 0, stream>>>(x, xb, s);
    int wblocks = (int)(((size_t)N_DIM * K_DIM / 8) / 256);   // 22016
    prep_w_kernel<<<wblocks, 256, 0, stream>>>(weight, wb);

    gemm_kernel<<<dim3((N_DIM / 256) * (M_DIM / 256)), dim3(512), 0, stream>>>(
        xb, wb, s, scale, offset, bias, y);
}

// Round 2
// 664.352 us; speedup vs baseline: 1.3792x; 1.0093x over previous
//
#include <hip/hip_runtime.h>
#include <hip/hip_bf16.h>
#include <cstdint>

#define M_DIM 4096
#define K_DIM 4096
#define N_DIM 11008
#define NT_K  (K_DIM / 64)          // 64 K-tiles of BK=64

typedef __attribute__((ext_vector_type(8))) short short8;
typedef __attribute__((ext_vector_type(4))) float floatx4;

__device__ __forceinline__ unsigned short f2bf(float f) {
    union { float f; unsigned u; } v; v.f = f;
    unsigned r = v.u + 0x7FFFu + ((v.u >> 16) & 1u);   // round-to-nearest-even
    return (unsigned short)(r >> 16);
}

__device__ __forceinline__ void async_copy16(const ushort* g, const ushort* l) {
    __builtin_amdgcn_global_load_lds(
        (const __attribute__((address_space(1))) void*)(uintptr_t)(const void*)g,
        (__attribute__((address_space(3))) void*)(uintptr_t)(const void*)l,
        16, 0, 0);
}

// ---------------------------------------------------------------------------
// Fused prep: blocks [0, M_DIM)             -> x fp32->bf16 + row sums
//             blocks [M_DIM, M_DIM+11008)   -> weight int32->bf16 (exact)
// One dispatch instead of two: saves a launch gap, overlaps both streams.
// ---------------------------------------------------------------------------
__global__ void prep_kernel(const float* __restrict__ x, const int* __restrict__ w,
                            ushort* __restrict__ xb, ushort* __restrict__ wb,
                            float* __restrict__ s) {
    const int tid = threadIdx.x;                 // 256 threads
    if (blockIdx.x < M_DIM) {
        const int row = blockIdx.x;
        const float*  xr = x  + (size_t)row * K_DIM;
        ushort*       xo = xb + (size_t)row * K_DIM;
        float sum = 0.f;
#pragma unroll
        for (int i = 0; i < 2; ++i) {
            int e = (tid + i * 256) * 8;         // 8 floats per unit
            float4 v0 = *(const float4*)(xr + e);
            float4 v1 = *(const float4*)(xr + e + 4);
            sum += v0.x + v0.y + v0.z + v0.w + v1.x + v1.y + v1.z + v1.w;
            short8 o;
            o[0] = f2bf(v0.x); o[1] = f2bf(v0.y); o[2] = f2bf(v0.z); o[3] = f2bf(v0.w);
            o[4] = f2bf(v1.x); o[5] = f2bf(v1.y); o[6] = f2bf(v1.z); o[7] = f2bf(v1.w);
            *(short8*)(xo + e) = o;
        }
#pragma unroll
        for (int off = 32; off > 0; off >>= 1) sum += __shfl_down(sum, off, 64);
        __shared__ float red[4];
        if ((tid & 63) == 0) red[tid >> 6] = sum;
        __syncthreads();
        if (tid == 0) s[row] = red[0] + red[1] + red[2] + red[3];
    } else {
        // 4096 ints per block, 16 ints (64B) per thread.
        const size_t base = (size_t)(blockIdx.x - M_DIM) * 4096;
        const int4* wi = (const int4*)w + (base >> 2) + tid * 4;
        short8*     wo = (short8*)wb + (base >> 3) + tid * 2;
#pragma unroll
        for (int h = 0; h < 2; ++h) {
            int4 v0 = wi[h * 2];
            int4 v1 = wi[h * 2 + 1];
            short8 o;
            o[0] = f2bf((float)v0.x); o[1] = f2bf((float)v0.y);
            o[2] = f2bf((float)v0.z); o[3] = f2bf((float)v0.w);
            o[4] = f2bf((float)v1.x); o[5] = f2bf((float)v1.y);
            o[6] = f2bf((float)v1.z); o[7] = f2bf((float)v1.w);
            wo[h] = o;
        }
    }
}

// ---------------------------------------------------------------------------
// 256x256 tile, BK=64, 8 waves (2M x 4N), 4 phases per K-tile.
// Pipelined fragments: phase q issues ds_reads for phase q+1, then MFMAs
// phase q (compiler emits exact counted lgkm waits -> LDS reads overlap MFMA).
// B(t) lives in registers for the whole tile; ph3 prefetches next tile's
// B + A-quad0 after the vmcnt(4)+barrier that makes slot c^1 visible.
// 4 barriers per K-tile. T2 chunk-XOR swizzle unchanged (0 bank conflicts).
// ---------------------------------------------------------------------------

#define BAR()                                   \
    __builtin_amdgcn_sched_barrier(0);          \
    __builtin_amdgcn_s_barrier();               \
    __builtin_amdgcn_sched_barrier(0)

#define LDA(dst, base, q)                                                     \
    _Pragma("unroll")                                                         \
    for (int fl = 0; fl < 2; ++fl)                                            \
        _Pragma("unroll")                                                     \
        for (int ks = 0; ks < 2; ++ks)                                        \
            dst[fl][ks] = *(const short8*)((const ushort*)(base) + aoff[ks] + (q) * 2048 + fl * 1024)

#define LDB(dst, base)                                                        \
    _Pragma("unroll")                                                         \
    for (int fn = 0; fn < 4; ++fn)                                            \
        _Pragma("unroll")                                                     \
        for (int ks = 0; ks < 2; ++ks)                                        \
            dst[fn][ks] = *(const short8*)((const ushort*)(base) + boff[ks] + fn * 1024)

#define MFMAQ(ar, bc, q)                                                      \
    __builtin_amdgcn_s_setprio(1);                                            \
    _Pragma("unroll")                                                         \
    for (int fl = 0; fl < 2; ++fl)                                            \
        _Pragma("unroll")                                                     \
        for (int fn = 0; fn < 4; ++fn)                                        \
            _Pragma("unroll")                                                 \
            for (int ks = 0; ks < 2; ++ks)                                    \
                acc[(q) * 2 + fl][fn] = __builtin_amdgcn_mfma_f32_16x16x32_bf16( \
                    ar[fl][ks], bc[fn][ks], acc[(q) * 2 + fl][fn], 0, 0, 0);  \
    __builtin_amdgcn_s_setprio(0)

// One K-tile: KA = k-offset of A(t+1), KB = k-offset of B(t+2).
// AR: A read slot; AW: A write slot (= next tile's A read slot);
// BW: B(t+2) write region; BRN: B(t+1) read region; BC/BN: b reg ping-pong.
#define TILE(KA, KB, AR, AW, BW, BRN, BC, BN)                                 \
    /* ph0 */                                                                 \
    BAR();                                                                    \
    async_copy16(aSrc + (KA),                      (AW) + sdst);              \
    async_copy16(aSrc + (size_t) 64 * K_DIM + (KA), (AW) + sdst + 4096);      \
    LDA(a1, AR, 1);                                                           \
    MFMAQ(a0, BC, 0);                                                         \
    /* ph1 */                                                                 \
    BAR();                                                                    \
    async_copy16(aSrc + (size_t)128 * K_DIM + (KA), (AW) + sdst + 8192);      \
    async_copy16(aSrc + (size_t)192 * K_DIM + (KA), (AW) + sdst + 12288);     \
    LDA(a0, AR, 2);                                                           \
    MFMAQ(a1, BC, 1);                                                         \
    /* ph2 */                                                                 \
    BAR();                                                                    \
    async_copy16(bSrc + (KB),                      (BW) + sdst);              \
    async_copy16(bSrc + (size_t) 64 * K_DIM + (KB), (BW) + sdst + 4096);      \
    LDA(a1, AR, 3);                                                           \
    MFMAQ(a0, BC, 2);                                                         \
    /* ph3: finish B(t+2) stage, make slot c^1 visible, prefetch next tile */ \
    async_copy16(bSrc + (size_t)128 * K_DIM + (KB), (BW) + sdst + 8192);      \
    async_copy16(bSrc + (size_t)192 * K_DIM + (KB), (BW) + sdst + 12288);     \
    asm volatile("s_waitcnt vmcnt(4)" ::: "memory");                          \
    BAR();                                                                    \
    LDB(BN, BRN);                                                             \
    LDA(a0, AW, 0);                                                           \
    MFMAQ(a1, BC, 3)

__global__ __launch_bounds__(512) void gemm_kernel(
        const ushort* __restrict__ xb, const ushort* __restrict__ wb,
        const float* __restrict__ s, const float* __restrict__ scale,
        const float* __restrict__ offset, const float* __restrict__ bias,
        float* __restrict__ y) {
    __shared__ ushort lds[2][2][256 * 64];     // 128 KiB

    const int tid  = threadIdx.x;
    const int lane = tid & 63;
    const int wave = tid >> 6;          // 0..7
    const int wm   = wave >> 2;         // 0..1  (M half)
    const int wn   = wave & 3;          // 0..3  (N quarter)
    const int r15  = lane & 15;
    const int quad = lane >> 4;

    // XCD-aware bijective swizzle: 688 blocks = 8 XCDs x 86 contiguous work-ids.
    const int wg  = blockIdx.x;
    const int swz = (wg & 7) * 86 + (wg >> 3);
    const int m0  = (swz & 15) * 256;
    const int n0  = (swz >> 4) * 256;

    // --- staging addressing (linear LDS dest, pre-swizzled global source) ---
    const int    srow = wave * 8 + (lane >> 3);
    const int    scol = ((lane & 7) ^ (lane >> 3)) * 8;
    const ushort* aSrc = xb + (size_t)(m0 + srow) * K_DIM + scol;
    const ushort* bSrc = wb + (size_t)(n0 + srow) * K_DIM + scol;
    const int    sdst = wave * 512;            // element offset (+ l*4096)

    // --- swizzled read offsets: chunk (ks*4+quad) ^ (row&7) ---
    const int x7 = r15 & 7;
    int aoff[2], boff[2];
#pragma unroll
    for (int ks = 0; ks < 2; ++ks) {
        aoff[ks] = (wm * 128 + r15) * 64 + ((ks * 4 + quad) ^ x7) * 8;
        boff[ks] = (wn *  64 + r15) * 64 + ((ks * 4 + quad) ^ x7) * 8;
    }

    ushort* lds0A = &lds[0][0][0];
    ushort* lds1A = &lds[1][0][0];
    ushort* lds0B = &lds[0][1][0];
    ushort* lds1B = &lds[1][1][0];

    floatx4 acc[8][4] = {};
    short8 a0[2][2], a1[2][2], b0[4][2], b1[4][2];

    // --- prologue: stage A(0),B(0) -> slot0; B(1) -> slot1; then preload
    //     tile-0 ph0 fragments (B(0) full + A(0) quad0). ---
#pragma unroll
    for (int l = 0; l < 4; ++l)
        async_copy16(aSrc + (size_t)l * 64 * K_DIM, lds0A + sdst + l * 4096);
#pragma unroll
    for (int l = 0; l < 4; ++l)
        async_copy16(bSrc + (size_t)l * 64 * K_DIM, lds0B + sdst + l * 4096);
#pragma unroll
    for (int l = 0; l < 4; ++l)
        async_copy16(bSrc + (size_t)l * 64 * K_DIM + 64, lds1B + sdst + l * 4096);
    asm volatile("s_waitcnt vmcnt(4)" ::: "memory");
    __builtin_amdgcn_s_barrier();
    LDB(b0, lds0B);
    LDA(a0, lds0A, 0);

    for (int t = 0; t < NT_K; t += 2) {
        // even tile t: read slot0, stage A(t+1)->slot1, B(t+2)->slot0 B
        const size_t ka0 = (size_t)(t + 1) * 64;                        // t+1 <= 63
        const size_t kb0 = (t + 2 < NT_K) ? (size_t)(t + 2) * 64 : 0;   // clamped
        TILE(ka0, kb0, lds0A, lds1A, lds0B, lds1B, b0, b1);
        // odd tile t+1: mirrored slots / b ping-pong
        const size_t ka1 = (t + 2 < NT_K) ? (size_t)(t + 2) * 64 : 0;
        const size_t kb1 = (t + 3 < NT_K) ? (size_t)(t + 3) * 64 : 0;
        TILE(ka1, kb1, lds1A, lds0A, lds1B, lds0B, b1, b0);
    }

    // ---- epilogue: y = scale*(acc + off*rowsum) + bias ----
    float sm[8][4];
#pragma unroll
    for (int fm = 0; fm < 8; ++fm)
#pragma unroll
        for (int r = 0; r < 4; ++r)
            sm[fm][r] = s[m0 + wm * 128 + fm * 16 + quad * 4 + r];

#pragma unroll
    for (int fn = 0; fn < 4; ++fn) {
        const int n = n0 + wn * 64 + fn * 16 + r15;
        const float sc = scale[n], of = offset[n], bi = bias[n];
#pragma unroll
        for (int fm = 0; fm < 8; ++fm) {
            const int mb = m0 + wm * 128 + fm * 16 + quad * 4;
#pragma unroll
            for (int r = 0; r < 4; ++r) {
                y[(size_t)(mb + r) * N_DIM + n] =
                    sc * (acc[fm][fn][r] + of * sm[fm][r]) + bi;
            }
        }
    }
}

extern "C" void kernel_launch(void* const* d_in, const int* in_sizes, int n_in,
                              void* d_out, int out_size, void* d_ws, size_t ws_size,
                              hipStream_t stream) {
    const float* x      = (const float*)d_in[0];
    const int*   weight = (const int*)d_in[1];
    const float* scale  = (const float*)d_in[2];
    const float* offset = (const float*)d_in[3];
    const float* bias   = (const float*)d_in[4];
    float*       y      = (float*)d_out;

    // Workspace layout (bytes): xb bf16 M*K | wb bf16 N*K | s fp32 M
    ushort* xb = (ushort*)d_ws;
    ushort* wb = (ushort*)((char*)d_ws + (size_t)M_DIM * K_DIM * 2);
    float*  s  = (float*)((char*)d_ws + (size_t)M_DIM * K_DIM * 2 + (size_t)N_DIM * K_DIM * 2);

    // x-rows (4096 blocks) + w-chunks (N*K/4096 = 11008 blocks) in one dispatch
    prep_kernel<<<M_DIM + (int)((size_t)N_DIM * K_DIM / 4096), 256, 0, stream>>>(
        x, weight, xb, wb, s);

    gemm_kernel<<<dim3((N_DIM / 256) * (M_DIM / 256)), dim3(512), 0, stream>>>(
        xb, wb, s, scale, offset, bias, y);
}